// Round 2
// baseline (121.696 us; speedup 1.0000x reference)
//
#include <hip/hip_runtime.h>

// GaussianUpsampling: out[b,f,a] = sum_t softmax_t(-0.1*(t_f - c_t)^2) * hs[b,t,a]
//   c = cumsum(ds) - ds/2 (token centers), t_f = f * h_mask[b,f]
// Strategy: Gaussian attention is local -- only tokens whose centers lie within
// ~sqrt(d_min^2+230) of the frame contribute >1e-10 relative weight. We window
// the softmax to tokens with centers in [t_min-16, t_max+16] per 16-frame tile
// (binary search on sorted centers) padded by +-16 tokens. Cuts einsum K from
// 512 to ~44 -> ~1.5 GFLOP (9 us vector floor) vs 17.2 GFLOP dense (110 us).
// R1 fix: masks arrive as int32 (harness passes integer types as int*), not
// 1-byte bool -- reading bytes made 3/4 of frames/tokens see mask=0.

namespace {
constexpr int kB = 16;      // batch
constexpr int kT = 512;     // T_text
constexpr int kA = 256;     // adim
constexpr int kF = 4096;    // T_feats
constexpr float kDelta = 0.1f;
constexpr int kFTile = 16;  // frames per block
constexpr int kRadius = 16; // center-distance inclusion radius (frames)
constexpr int kPad = 16;    // extra token padding each side of the range
// weights stored [token][frame]; stride 20 floats keeps float4 reads 16B-aligned
// and staggers banks (2-way aliasing only, which is free on gfx950).
constexpr int kWStride = kFTile + 4;
}

// Kernel 1: exact sequential fp32 cumsum per batch (matches CPU-reference
// association; 512-add dependency chain ~1-2us across 16 concurrent blocks).
__global__ __launch_bounds__(64) void centers_kernel(
    const float* __restrict__ ds, float* __restrict__ c) {
  __shared__ float s_ds[kT];
  __shared__ float s_c[kT];
  const int b = blockIdx.x;
  const float* dsb = ds + (size_t)b * kT;
  for (int j = threadIdx.x; j < kT; j += 64) s_ds[j] = dsb[j];
  __syncthreads();
  if (threadIdx.x == 0) {
    float acc = 0.0f;
    for (int j = 0; j < kT; ++j) {
      float d = s_ds[j];
      acc += d;
      s_c[j] = acc - 0.5f * d;
    }
  }
  __syncthreads();
  float* cb = c + (size_t)b * kT;
  for (int j = threadIdx.x; j < kT; j += 64) cb[j] = s_c[j];
}

// Kernel 2: one block = (b, 16-frame tile), 256 threads.
// Phase A: 16 groups x 16 lanes compute windowed softmax weights into LDS.
// Phase B: thread = 4 frames x 4 channels; per token: 1 ds_read_b128 (weights,
// uniform broadcast per wave) + 1 global_load_dwordx4 (hs, coalesced) + 16 FMA.
__global__ __launch_bounds__(256) void upsample_kernel(
    const float* __restrict__ hs, const float* __restrict__ c,
    const int* __restrict__ h_masks,
    const int* __restrict__ d_masks,
    float* __restrict__ out) {
  __shared__ float s_c[kT];
  __shared__ int s_dm[kT];
  __shared__ float s_w[kT * kWStride];   // 40 KB worst case (K can reach 512)
  __shared__ float s_t[kFTile];
  __shared__ float s_rsum[kFTile];

  const int b = blockIdx.y;
  const int f0 = blockIdx.x * kFTile;
  const int tid = threadIdx.x;

  for (int j = tid; j < kT; j += 256) {
    s_c[j] = c[(size_t)b * kT + j];
    s_dm[j] = d_masks[(size_t)b * kT + j];
  }

  const int g = tid >> 4;   // frame group 0..15
  const int l = tid & 15;   // lane within group
  const int f = f0 + g;
  const float tf = h_masks[(size_t)b * kF + f] ? (float)f : 0.0f;
  if (l == 0) s_t[g] = tf;
  __syncthreads();

  // --- window selection (uniform across block; redundant per-thread) ---
  float tmin = s_t[0], tmax = s_t[0];
#pragma unroll
  for (int i = 1; i < kFTile; ++i) {
    tmin = fminf(tmin, s_t[i]);
    tmax = fmaxf(tmax, s_t[i]);
  }
  const float lo = tmin - (float)kRadius;
  const float hi = tmax + (float)kRadius;
  int jlo, jhi;
  {  // lower_bound: first j with c[j] >= lo
    int a = 0, e = kT;
    while (a < e) { int m = (a + e) >> 1; if (s_c[m] < lo) a = m + 1; else e = m; }
    jlo = a;
  }
  {  // upper_bound: first j with c[j] > hi
    int a = 0, e = kT;
    while (a < e) { int m = (a + e) >> 1; if (s_c[m] <= hi) a = m + 1; else e = m; }
    jhi = a;
  }
  jlo = max(0, jlo - kPad);
  jhi = min(kT, jhi + kPad);
  const int K = jhi - jlo;   // >= 16 by construction

  // --- Phase A: energies -> unnormalized softmax weights in LDS ---
  float m = -1e38f;
  for (int jj = l; jj < K; jj += 16) {
    const int j = jlo + jj;
    const float d = tf - s_c[j];
    float e = -kDelta * d * d;
    if (!s_dm[j]) e = -1e30f;   // masked token -> weight 0 after exp
    s_w[jj * kWStride + g] = e;
    m = fmaxf(m, e);
  }
#pragma unroll
  for (int off = 8; off >= 1; off >>= 1) m = fmaxf(m, __shfl_xor(m, off, 16));
  float ssum = 0.0f;
  for (int jj = l; jj < K; jj += 16) {
    const float e = s_w[jj * kWStride + g];
    const float w = __expf(e - m);
    s_w[jj * kWStride + g] = w;
    ssum += w;
  }
#pragma unroll
  for (int off = 8; off >= 1; off >>= 1) ssum += __shfl_xor(ssum, off, 16);
  if (l == 0) s_rsum[g] = 1.0f / ssum;
  __syncthreads();

  // --- Phase B: windowed einsum ---
  const int q = tid >> 6;          // frame quad 0..3 (uniform within a wave)
  const int ch = (tid & 63) << 2;  // channel base, float4 per thread
  const float* hsb = hs + (size_t)b * kT * kA + ch;
  float acc[4][4];
#pragma unroll
  for (int i = 0; i < 4; ++i)
#pragma unroll
    for (int k = 0; k < 4; ++k) acc[i][k] = 0.0f;

  for (int jj = 0; jj < K; ++jj) {
    const float4 h4 = *reinterpret_cast<const float4*>(hsb + (size_t)(jlo + jj) * kA);
    const float4 w4 = *reinterpret_cast<const float4*>(&s_w[jj * kWStride + 4 * q]);
    const float hf[4] = {h4.x, h4.y, h4.z, h4.w};
    const float wf[4] = {w4.x, w4.y, w4.z, w4.w};
#pragma unroll
    for (int i = 0; i < 4; ++i)
#pragma unroll
      for (int k = 0; k < 4; ++k) acc[i][k] += wf[i] * hf[k];
  }

  float* ob = out + ((size_t)b * kF + (size_t)(f0 + 4 * q)) * kA + ch;
#pragma unroll
  for (int i = 0; i < 4; ++i) {
    const float r = s_rsum[4 * q + i];
    float4 o;
    o.x = acc[i][0] * r; o.y = acc[i][1] * r;
    o.z = acc[i][2] * r; o.w = acc[i][3] * r;
    *reinterpret_cast<float4*>(ob + (size_t)i * kA) = o;
  }
}

extern "C" void kernel_launch(void* const* d_in, const int* in_sizes, int n_in,
                              void* d_out, int out_size, void* d_ws, size_t ws_size,
                              hipStream_t stream) {
  const float* hs = (const float*)d_in[0];            // (16, 512, 256) fp32
  const float* ds = (const float*)d_in[1];            // (16, 512) fp32
  const int* h_masks = (const int*)d_in[2];           // (16, 4096) bool -> int32
  const int* d_masks = (const int*)d_in[3];           // (16, 512) bool -> int32
  float* out = (float*)d_out;                          // (16, 4096, 256) fp32
  float* c = (float*)d_ws;                             // 16*512 floats scratch

  centers_kernel<<<kB, 64, 0, stream>>>(ds, c);
  upsample_kernel<<<dim3(kF / kFTile, kB), 256, 0, stream>>>(hs, c, h_masks, d_masks, out);
}

// Round 4
// 101.106 us; speedup vs baseline: 1.2036x; 1.2036x over previous
//
#include <hip/hip_runtime.h>

// GaussianUpsampling: out[b,f,a] = sum_t softmax_t(-0.1*(t_f - c_t)^2) * hs[b,t,a]
//   c = cumsum(ds) - ds/2, t_f = f * h_mask[b,f]
// R2 -> R3 (R4 fixes compile: __builtin_nontemporal_store needs a native
// clang vector, not HIP's float4 class -- use ext_vector_type(4)):
//  - centers_kernel (serial cumsum, ~65us!) removed: parallel shuffle-scan
//    fused into each block (fp32 assoc. change ~1e-4 in c -> ~1e-3 in out).
//  - LDS 45.5KB -> 19.6KB (cap K at 192; expected K~44) => 3 -> ~7 blocks/CU.
//  - Window padded to multiple of 4 with real tokens; Phase B unrolled x4.
//  - 1D grid, b = id&15: same-batch blocks land on the same XCD (i%8 round
//    robin heuristic) for hs L2 reuse; non-temporal out stores keep L2 clean.

namespace {
constexpr int kB = 16;      // batch
constexpr int kT = 512;     // T_text
constexpr int kA = 256;     // adim
constexpr int kF = 4096;    // T_feats
constexpr float kDelta = 0.1f;
constexpr int kFTile = 16;  // frames per block
constexpr int kRadius = 16; // center-distance inclusion radius (frames)
constexpr int kPad = 16;    // extra token padding each side
constexpr int kMaxK = 192;  // window cap (multiple of 4); expected K ~ 44
constexpr int kWStride = kFTile + 4;  // [token][frame] stride: 16B-aligned, 2-way bank alias (free)
typedef float f32x4 __attribute__((ext_vector_type(4)));  // native vec for nontemporal store
}

__global__ __launch_bounds__(256, 6) void upsample_kernel(
    const float* __restrict__ hs, const float* __restrict__ ds,
    const int* __restrict__ h_masks, const int* __restrict__ d_masks,
    float* __restrict__ out) {
  __shared__ __align__(16) float s_c[kT];
  __shared__ int s_dm[kT];
  __shared__ __align__(16) float s_w[kMaxK * kWStride];  // 15.4 KB
  __shared__ float s_t[kFTile];
  __shared__ float s_rsum[kFTile];
  __shared__ float s_wsum[4];

  const int id = blockIdx.x;
  const int b = id & 15;        // batch in low bits => same batch -> same XCD (id%8)
  const int f0 = (id >> 4) * kFTile;
  const int tid = threadIdx.x;
  const int wave = tid >> 6, lane = tid & 63;

  // --- fused token-center scan: thread t covers ds[2t], ds[2t+1] ---
  const float2 dsv = *reinterpret_cast<const float2*>(ds + (size_t)b * kT + 2 * tid);
  const float psum = dsv.x + dsv.y;
  float incl = psum;
#pragma unroll
  for (int off = 1; off < 64; off <<= 1) {
    float u = __shfl_up(incl, off, 64);
    if (lane >= off) incl += u;
  }
  if (lane == 63) s_wsum[wave] = incl;

  for (int j = tid; j < kT; j += 256) s_dm[j] = d_masks[(size_t)b * kT + j];

  const int g = tid >> 4;   // frame group 0..15
  const int l = tid & 15;   // lane within group
  const int f = f0 + g;
  const float tf = h_masks[(size_t)b * kF + f] ? (float)f : 0.0f;
  __syncthreads();

  float basesum = 0.0f;
#pragma unroll
  for (int w = 0; w < 4; ++w)
    if (w < wave) basesum += s_wsum[w];
  const float excl = basesum + incl - psum;
  s_c[2 * tid]     = excl + 0.5f * dsv.x;
  s_c[2 * tid + 1] = excl + dsv.x + 0.5f * dsv.y;
  if (l == 0) s_t[g] = tf;
  __syncthreads();

  // --- window selection (uniform across block) ---
  float tmin = s_t[0], tmax = s_t[0];
#pragma unroll
  for (int i = 1; i < kFTile; ++i) {
    tmin = fminf(tmin, s_t[i]);
    tmax = fmaxf(tmax, s_t[i]);
  }
  const float lo = tmin - (float)kRadius;
  const float hi = tmax + (float)kRadius;
  int jlo, jhi;
  {  // lower_bound: first j with c[j] >= lo
    int a = 0, e = kT;
    while (a < e) { int mm = (a + e) >> 1; if (s_c[mm] < lo) a = mm + 1; else e = mm; }
    jlo = a;
  }
  {  // upper_bound: first j with c[j] > hi
    int a = 0, e = kT;
    while (a < e) { int mm = (a + e) >> 1; if (s_c[mm] <= hi) a = mm + 1; else e = mm; }
    jhi = a;
  }
  jlo = max(0, jlo - kPad);
  jhi = min(kT, jhi + kPad);
  int K = jhi - jlo;
  if (K > kMaxK) {  // keep the central (highest-weight) tokens
    jlo += (K - kMaxK) >> 1;
    jhi = jlo + kMaxK;
    K = kMaxK;
  }
  {  // pad K to a multiple of 4 with real in-range tokens (weights ~0 anyway)
    const int ext = (4 - (K & 3)) & 3;
    if (jhi + ext <= kT) jhi += ext; else jlo -= ext;  // jlo >= 318 when jhi > 509
    K += ext;
  }

  // --- Phase A: windowed softmax weights into LDS [token][frame] ---
  float m = -1e38f;
  for (int jj = l; jj < K; jj += 16) {
    const int j = jlo + jj;
    const float d = tf - s_c[j];
    float e = -kDelta * d * d;
    if (!s_dm[j]) e = -1e30f;
    s_w[jj * kWStride + g] = e;
    m = fmaxf(m, e);
  }
#pragma unroll
  for (int off = 8; off >= 1; off >>= 1) m = fmaxf(m, __shfl_xor(m, off, 16));
  float ssum = 0.0f;
  for (int jj = l; jj < K; jj += 16) {
    const float w = __expf(s_w[jj * kWStride + g] - m);
    s_w[jj * kWStride + g] = w;
    ssum += w;
  }
#pragma unroll
  for (int off = 8; off >= 1; off >>= 1) ssum += __shfl_xor(ssum, off, 16);
  if (l == 0) s_rsum[g] = 1.0f / ssum;
  __syncthreads();

  // --- Phase B: windowed einsum, unroll x4 (K % 4 == 0) ---
  const int q = tid >> 6;          // frame quad (wave-uniform) -> LDS broadcast
  const int ch = (tid & 63) << 2;  // float4 channel slice, coalesced
  const float* hp = hs + ((size_t)b * kT + jlo) * kA + ch;
  const float* wp = s_w + 4 * q;
  float acc[4][4];
#pragma unroll
  for (int i = 0; i < 4; ++i)
#pragma unroll
    for (int k = 0; k < 4; ++k) acc[i][k] = 0.0f;

  for (int jj = 0; jj < K; jj += 4) {
    const float4 h0 = *reinterpret_cast<const float4*>(hp);
    const float4 h1 = *reinterpret_cast<const float4*>(hp + kA);
    const float4 h2 = *reinterpret_cast<const float4*>(hp + 2 * kA);
    const float4 h3 = *reinterpret_cast<const float4*>(hp + 3 * kA);
    const float4 w0 = *reinterpret_cast<const float4*>(wp);
    const float4 w1 = *reinterpret_cast<const float4*>(wp + kWStride);
    const float4 w2 = *reinterpret_cast<const float4*>(wp + 2 * kWStride);
    const float4 w3 = *reinterpret_cast<const float4*>(wp + 3 * kWStride);
    const float hf0[4] = {h0.x, h0.y, h0.z, h0.w};
    const float hf1[4] = {h1.x, h1.y, h1.z, h1.w};
    const float hf2[4] = {h2.x, h2.y, h2.z, h2.w};
    const float hf3[4] = {h3.x, h3.y, h3.z, h3.w};
    const float wf0[4] = {w0.x, w0.y, w0.z, w0.w};
    const float wf1[4] = {w1.x, w1.y, w1.z, w1.w};
    const float wf2[4] = {w2.x, w2.y, w2.z, w2.w};
    const float wf3[4] = {w3.x, w3.y, w3.z, w3.w};
#pragma unroll
    for (int i = 0; i < 4; ++i)
#pragma unroll
      for (int k = 0; k < 4; ++k) {
        acc[i][k] += wf0[i] * hf0[k];
        acc[i][k] += wf1[i] * hf1[k];
        acc[i][k] += wf2[i] * hf2[k];
        acc[i][k] += wf3[i] * hf3[k];
      }
    hp += 4 * kA;
    wp += 4 * kWStride;
  }

  float* ob = out + ((size_t)b * kF + (size_t)(f0 + 4 * q)) * kA + ch;
#pragma unroll
  for (int i = 0; i < 4; ++i) {
    const float r = s_rsum[4 * q + i];
    f32x4 o;
    o.x = acc[i][0] * r; o.y = acc[i][1] * r;
    o.z = acc[i][2] * r; o.w = acc[i][3] * r;
    __builtin_nontemporal_store(o, reinterpret_cast<f32x4*>(ob + (size_t)i * kA));
  }
}

extern "C" void kernel_launch(void* const* d_in, const int* in_sizes, int n_in,
                              void* d_out, int out_size, void* d_ws, size_t ws_size,
                              hipStream_t stream) {
  const float* hs = (const float*)d_in[0];   // (16, 512, 256) fp32
  const float* ds = (const float*)d_in[1];   // (16, 512) fp32
  const int* h_masks = (const int*)d_in[2];  // (16, 4096) bool -> int32
  const int* d_masks = (const int*)d_in[3];  // (16, 512) bool -> int32
  float* out = (float*)d_out;                // (16, 4096, 256) fp32

  upsample_kernel<<<kB * (kF / kFTile), 256, 0, stream>>>(hs, ds, h_masks, d_masks, out);
}

// Round 5
// 90.780 us; speedup vs baseline: 1.3406x; 1.1137x over previous
//
#include <hip/hip_runtime.h>

// GaussianUpsampling: out[b,f,a] = sum_t softmax_t(-0.1*(t_f - c_t)^2) * hs[b,t,a]
//   c = cumsum(ds) - ds/2, t_f = f * h_mask[b,f]
// Measurement model (R4): dur_us includes ~64us of harness poison/restore
// (268MB ws-fill + 67MB out-fill + input restore); upsample itself ~37us.
// R4 -> R5:
//  - radius 16->10, pad 16->4: truncation err ~2e-4 << 0.089 threshold.
//    K ~44 -> ~24 near; frames past the last token center (HALF the output,
//    sum(ds)~2048 < 4096) collapse to K=4 -> kernel ~store-bound.
//  - kMaxK 192->128: LDS 19.8->14.5 KB, launch_bounds (256,6)->(256,7).
//  - dual binary searches fused/interleaved: overlap the ~120cyc dependent
//    LDS latencies (dominated block time for far, K=4 blocks).

namespace {
constexpr int kB = 16;      // batch
constexpr int kT = 512;     // T_text
constexpr int kA = 256;     // adim
constexpr int kF = 4096;    // T_feats
constexpr float kDelta = 0.1f;
constexpr int kFTile = 16;  // frames per block
constexpr int kRadius = 10; // center-distance inclusion radius (frames); rel wt exp(-10)=4.5e-5
constexpr int kPad = 4;     // extra token padding each side
constexpr int kMaxK = 128;  // window cap (multiple of 4); realistic K <= ~32
constexpr int kWStride = kFTile + 4;  // [token][frame] stride: 16B-aligned, 2-way bank alias (free)
typedef float f32x4 __attribute__((ext_vector_type(4)));  // native vec for nontemporal store
}

__global__ __launch_bounds__(256, 7) void upsample_kernel(
    const float* __restrict__ hs, const float* __restrict__ ds,
    const int* __restrict__ h_masks, const int* __restrict__ d_masks,
    float* __restrict__ out) {
  __shared__ __align__(16) float s_c[kT];
  __shared__ int s_dm[kT];
  __shared__ __align__(16) float s_w[kMaxK * kWStride];  // 10.2 KB
  __shared__ float s_t[kFTile];
  __shared__ float s_rsum[kFTile];
  __shared__ float s_wsum[4];

  const int id = blockIdx.x;
  const int b = id & 15;        // batch in low bits => same batch -> same XCD (id%8)
  const int f0 = (id >> 4) * kFTile;
  const int tid = threadIdx.x;
  const int wave = tid >> 6, lane = tid & 63;

  // --- fused token-center scan: thread t covers ds[2t], ds[2t+1] ---
  const float2 dsv = *reinterpret_cast<const float2*>(ds + (size_t)b * kT + 2 * tid);
  const float psum = dsv.x + dsv.y;
  float incl = psum;
#pragma unroll
  for (int off = 1; off < 64; off <<= 1) {
    float u = __shfl_up(incl, off, 64);
    if (lane >= off) incl += u;
  }
  if (lane == 63) s_wsum[wave] = incl;

  for (int j = tid; j < kT; j += 256) s_dm[j] = d_masks[(size_t)b * kT + j];

  const int g = tid >> 4;   // frame group 0..15
  const int l = tid & 15;   // lane within group
  const int f = f0 + g;
  const float tf = h_masks[(size_t)b * kF + f] ? (float)f : 0.0f;
  __syncthreads();

  float basesum = 0.0f;
#pragma unroll
  for (int w = 0; w < 4; ++w)
    if (w < wave) basesum += s_wsum[w];
  const float excl = basesum + incl - psum;
  s_c[2 * tid]     = excl + 0.5f * dsv.x;
  s_c[2 * tid + 1] = excl + dsv.x + 0.5f * dsv.y;
  if (l == 0) s_t[g] = tf;
  __syncthreads();

  // --- window selection (uniform across block) ---
  float tmin = s_t[0], tmax = s_t[0];
#pragma unroll
  for (int i = 1; i < kFTile; ++i) {
    tmin = fminf(tmin, s_t[i]);
    tmax = fmaxf(tmax, s_t[i]);
  }
  const float lo = tmin - (float)kRadius;
  const float hi = tmax + (float)kRadius;
  // fused dual binary search: probes are independent -> latencies overlap
  int alo = 0, elo = kT;   // lower_bound: first j with c[j] >= lo
  int ahi = 0, ehi = kT;   // upper_bound: first j with c[j] > hi
#pragma unroll
  for (int it = 0; it < 9; ++it) {  // ceil(log2(512)) = 9 halvings each
    const int m1 = (alo + elo) >> 1;
    const int m2 = (ahi + ehi) >> 1;
    const float c1 = s_c[m1];
    const float c2 = s_c[m2];
    if (alo < elo) { if (c1 < lo) alo = m1 + 1; else elo = m1; }
    if (ahi < ehi) { if (c2 <= hi) ahi = m2 + 1; else ehi = m2; }
  }
  int jlo = max(0, alo - kPad);
  int jhi = min(kT, ahi + kPad);
  int K = jhi - jlo;
  if (K > kMaxK) {  // keep the central (highest-weight) tokens
    jlo += (K - kMaxK) >> 1;
    jhi = jlo + kMaxK;
    K = kMaxK;
  }
  {  // pad K to a multiple of 4 with real in-range tokens (weights ~0 anyway)
    const int ext = (4 - (K & 3)) & 3;
    if (jhi + ext <= kT) jhi += ext; else jlo -= ext;
    K += ext;
  }

  // --- Phase A: windowed softmax weights into LDS [token][frame] ---
  float m = -1e38f;
  for (int jj = l; jj < K; jj += 16) {
    const int j = jlo + jj;
    const float d = tf - s_c[j];
    float e = -kDelta * d * d;
    if (!s_dm[j]) e = -1e30f;
    s_w[jj * kWStride + g] = e;
    m = fmaxf(m, e);
  }
#pragma unroll
  for (int off = 8; off >= 1; off >>= 1) m = fmaxf(m, __shfl_xor(m, off, 16));
  float ssum = 0.0f;
  for (int jj = l; jj < K; jj += 16) {
    const float w = __expf(s_w[jj * kWStride + g] - m);
    s_w[jj * kWStride + g] = w;
    ssum += w;
  }
#pragma unroll
  for (int off = 8; off >= 1; off >>= 1) ssum += __shfl_xor(ssum, off, 16);
  if (l == 0) s_rsum[g] = 1.0f / ssum;
  __syncthreads();

  // --- Phase B: windowed einsum, unroll x4 (K % 4 == 0) ---
  const int q = tid >> 6;          // frame quad (wave-uniform) -> LDS broadcast
  const int ch = (tid & 63) << 2;  // float4 channel slice, coalesced
  const float* hp = hs + ((size_t)b * kT + jlo) * kA + ch;
  const float* wp = s_w + 4 * q;
  float acc[4][4];
#pragma unroll
  for (int i = 0; i < 4; ++i)
#pragma unroll
    for (int k = 0; k < 4; ++k) acc[i][k] = 0.0f;

  for (int jj = 0; jj < K; jj += 4) {
    const float4 h0 = *reinterpret_cast<const float4*>(hp);
    const float4 h1 = *reinterpret_cast<const float4*>(hp + kA);
    const float4 h2 = *reinterpret_cast<const float4*>(hp + 2 * kA);
    const float4 h3 = *reinterpret_cast<const float4*>(hp + 3 * kA);
    const float4 w0 = *reinterpret_cast<const float4*>(wp);
    const float4 w1 = *reinterpret_cast<const float4*>(wp + kWStride);
    const float4 w2 = *reinterpret_cast<const float4*>(wp + 2 * kWStride);
    const float4 w3 = *reinterpret_cast<const float4*>(wp + 3 * kWStride);
    const float hf0[4] = {h0.x, h0.y, h0.z, h0.w};
    const float hf1[4] = {h1.x, h1.y, h1.z, h1.w};
    const float hf2[4] = {h2.x, h2.y, h2.z, h2.w};
    const float hf3[4] = {h3.x, h3.y, h3.z, h3.w};
    const float wf0[4] = {w0.x, w0.y, w0.z, w0.w};
    const float wf1[4] = {w1.x, w1.y, w1.z, w1.w};
    const float wf2[4] = {w2.x, w2.y, w2.z, w2.w};
    const float wf3[4] = {w3.x, w3.y, w3.z, w3.w};
#pragma unroll
    for (int i = 0; i < 4; ++i)
#pragma unroll
      for (int k = 0; k < 4; ++k) {
        acc[i][k] += wf0[i] * hf0[k];
        acc[i][k] += wf1[i] * hf1[k];
        acc[i][k] += wf2[i] * hf2[k];
        acc[i][k] += wf3[i] * hf3[k];
      }
    hp += 4 * kA;
    wp += 4 * kWStride;
  }

  float* ob = out + ((size_t)b * kF + (size_t)(f0 + 4 * q)) * kA + ch;
#pragma unroll
  for (int i = 0; i < 4; ++i) {
    const float r = s_rsum[4 * q + i];
    f32x4 o;
    o.x = acc[i][0] * r; o.y = acc[i][1] * r;
    o.z = acc[i][2] * r; o.w = acc[i][3] * r;
    __builtin_nontemporal_store(o, reinterpret_cast<f32x4*>(ob + (size_t)i * kA));
  }
}

extern "C" void kernel_launch(void* const* d_in, const int* in_sizes, int n_in,
                              void* d_out, int out_size, void* d_ws, size_t ws_size,
                              hipStream_t stream) {
  const float* hs = (const float*)d_in[0];   // (16, 512, 256) fp32
  const float* ds = (const float*)d_in[1];   // (16, 512) fp32
  const int* h_masks = (const int*)d_in[2];  // (16, 4096) bool -> int32
  const int* d_masks = (const int*)d_in[3];  // (16, 512) bool -> int32
  float* out = (float*)d_out;                // (16, 4096, 256) fp32

  upsample_kernel<<<kB * (kF / kFTile), 256, 0, stream>>>(hs, ds, h_masks, d_masks, out);
}